// Round 2
// baseline (625.813 us; speedup 1.0000x reference)
//
#include <hip/hip_runtime.h>
#include <hip/hip_bf16.h>
#include <stdint.h>

typedef float f32x4 __attribute__((ext_vector_type(4)));
typedef __bf16 bf16x8 __attribute__((ext_vector_type(8)));
typedef __bf16 bf16x4 __attribute__((ext_vector_type(4)));

#define GLDS16(gp, lp) __builtin_amdgcn_global_load_lds( \
    (const __attribute__((address_space(1))) void*)(gp), \
    (__attribute__((address_space(3))) void*)(lp), 16, 0, 0)

// ---------------- cast fp32 -> bf16, vectorized x8 ----------------
__global__ __launch_bounds__(256) void k_cast_bf16(const float* __restrict__ in,
                                                   __bf16* __restrict__ out, long n) {
  long idx = ((long)blockIdx.x * blockDim.x + threadIdx.x) * 8;
  if (idx >= n) return;
  float4 a = *(const float4*)(in + idx);
  float4 b = *(const float4*)(in + idx + 4);
  bf16x8 o;
  o[0] = (__bf16)a.x; o[1] = (__bf16)a.y; o[2] = (__bf16)a.z; o[3] = (__bf16)a.w;
  o[4] = (__bf16)b.x; o[5] = (__bf16)b.y; o[6] = (__bf16)b.z; o[7] = (__bf16)b.w;
  *(bf16x8*)(out + idx) = o;
}

// ------------- transpose + cast: W[K][N] f32 -> WT[N][K] bf16 -------------
__global__ __launch_bounds__(256) void k_transpose_cast(const float* __restrict__ W,
                                                        __bf16* __restrict__ WT,
                                                        int K, int N) {
  __shared__ float tile[32][33];
  int n0 = blockIdx.x * 32, k0 = blockIdx.y * 32;
  int tx = threadIdx.x & 31, ty = threadIdx.x >> 5;  // ty 0..7
  #pragma unroll
  for (int r = 0; r < 32; r += 8)
    tile[ty + r][tx] = W[(long)(k0 + ty + r) * N + n0 + tx];
  __syncthreads();
  #pragma unroll
  for (int r = 0; r < 32; r += 8)
    WT[(long)(n0 + ty + r) * K + k0 + tx] = (__bf16)tile[tx][ty + r];
}

// ---------------- GEMM: C[m][n] = scale * sum_k A[m][k]*B[n][k] ----------------
// A: [M][K] bf16 (lda), B: [N][K] bf16 (ldb). Batched via gridDim.z + strides.
// OUT_MODE: 0 = f32 C[m][n], 1 = bf16 C[m][n], 2 = bf16 transposed C[n][m] (ldc = M-pitch)
// Tile 128x128, BK=32, 256 threads (4 waves), each wave 64x64 = 4x4 frags of 16x16x32.
template <int OUT_MODE>
__global__ __launch_bounds__(256) void k_gemm_bt(
    const __bf16* __restrict__ A, const __bf16* __restrict__ B, void* __restrict__ Cv,
    int lda, int ldb, int ldc, int K, float scale, long sA, long sB, long sC) {
  __shared__ __align__(16) __bf16 As[128 * 32];
  __shared__ __align__(16) __bf16 Bs[128 * 32];
  const int bz = blockIdx.z;
  A += (long)bz * sA;
  B += (long)bz * sB;
  const int m0 = blockIdx.y * 128, n0 = blockIdx.x * 128;
  const int tid = threadIdx.x;
  const int w = tid >> 6, lane = tid & 63;
  const int wm = w >> 1, wn = w & 1;
  const int g = lane >> 4, r = lane & 15;
  // staging: per wave 2 calls/tile; lane covers row = w*32 + call*16 + lane/4, col = (lane&3)*8
  const int srow = w * 32 + (lane >> 2);
  const int scol = (lane & 3) * 8;

  const __bf16* Ag = A + (long)(m0 + srow) * lda + scol;
  const __bf16* Bg = B + (long)(n0 + srow) * ldb + scol;
  __bf16* Asw = As + w * 1024;
  __bf16* Bsw = Bs + w * 1024;

  f32x4 acc[4][4] = {};

  for (int k0 = 0; k0 < K; k0 += 32) {
    GLDS16(Ag, Asw);
    GLDS16(Ag + (long)16 * lda, Asw + 512);
    GLDS16(Bg, Bsw);
    GLDS16(Bg + (long)16 * ldb, Bsw + 512);
    Ag += 32;
    Bg += 32;
    __syncthreads();  // compiler drains vmcnt before barrier -> LDS valid
    const bf16x8* Av = (const bf16x8*)As;
    const bf16x8* Bv = (const bf16x8*)Bs;
    bf16x8 af[4], bfv[4];
    #pragma unroll
    for (int i = 0; i < 4; ++i) af[i] = Av[(wm * 64 + i * 16 + r) * 4 + g];
    #pragma unroll
    for (int j = 0; j < 4; ++j) bfv[j] = Bv[(wn * 64 + j * 16 + r) * 4 + g];
    #pragma unroll
    for (int i = 0; i < 4; ++i)
      #pragma unroll
      for (int j = 0; j < 4; ++j)
        acc[i][j] = __builtin_amdgcn_mfma_f32_16x16x32_bf16(af[i], bfv[j], acc[i][j], 0, 0, 0);
    __syncthreads();
  }

  // C/D frag mapping (verified): col = lane&15, row = (lane>>4)*4 + reg
  const int crow = m0 + wm * 64 + g * 4;
  const int ccol = n0 + wn * 64 + r;
  if constexpr (OUT_MODE == 0) {
    float* C = (float*)Cv + (long)bz * sC;
    #pragma unroll
    for (int i = 0; i < 4; ++i)
      #pragma unroll
      for (int j = 0; j < 4; ++j)
        #pragma unroll
        for (int rr = 0; rr < 4; ++rr)
          C[(long)(crow + i * 16 + rr) * ldc + ccol + j * 16] = acc[i][j][rr] * scale;
  } else if constexpr (OUT_MODE == 1) {
    __bf16* C = (__bf16*)Cv + (long)bz * sC;
    #pragma unroll
    for (int i = 0; i < 4; ++i)
      #pragma unroll
      for (int j = 0; j < 4; ++j)
        #pragma unroll
        for (int rr = 0; rr < 4; ++rr)
          C[(long)(crow + i * 16 + rr) * ldc + ccol + j * 16] =
              (__bf16)(acc[i][j][rr] * scale);
  } else {
    // transposed write: CT[n][m]; 4 regs are 4 consecutive m -> one 8B store
    __bf16* C = (__bf16*)Cv + (long)bz * sC;
    #pragma unroll
    for (int i = 0; i < 4; ++i)
      #pragma unroll
      for (int j = 0; j < 4; ++j) {
        bf16x4 p;
        #pragma unroll
        for (int rr = 0; rr < 4; ++rr) p[rr] = (__bf16)(acc[i][j][rr] * scale);
        *(bf16x4*)&C[(long)(ccol + j * 16) * ldc + crow + i * 16] = p;
      }
  }
}

// ---------------- row softmax, fp32 in, bf16 out written in-place ----------------
// one block per row of 2048 f32; attn bf16 occupies first half of the same row.
__global__ __launch_bounds__(256) void k_softmax_rows(float* __restrict__ scores) {
  long row = blockIdx.x;
  float* src = scores + row * 2048;
  __bf16* dst = (__bf16*)src;
  int t = threadIdx.x, w = t >> 6, lane = t & 63;
  float4 v0 = *(const float4*)(src + t * 8);
  float4 v1 = *(const float4*)(src + t * 8 + 4);
  float vm = fmaxf(fmaxf(fmaxf(v0.x, v0.y), fmaxf(v0.z, v0.w)),
                   fmaxf(fmaxf(v1.x, v1.y), fmaxf(v1.z, v1.w)));
  #pragma unroll
  for (int off = 1; off < 64; off <<= 1) vm = fmaxf(vm, __shfl_xor(vm, off));
  __shared__ float redm[4], reds[4];
  if (lane == 0) redm[w] = vm;
  __syncthreads();
  vm = fmaxf(fmaxf(redm[0], redm[1]), fmaxf(redm[2], redm[3]));
  float e[8];
  e[0] = __expf(v0.x - vm); e[1] = __expf(v0.y - vm);
  e[2] = __expf(v0.z - vm); e[3] = __expf(v0.w - vm);
  e[4] = __expf(v1.x - vm); e[5] = __expf(v1.y - vm);
  e[6] = __expf(v1.z - vm); e[7] = __expf(v1.w - vm);
  float s = ((e[0] + e[1]) + (e[2] + e[3])) + ((e[4] + e[5]) + (e[6] + e[7]));
  #pragma unroll
  for (int off = 1; off < 64; off <<= 1) s += __shfl_xor(s, off);
  if (lane == 0) reds[w] = s;
  __syncthreads();
  s = (reds[0] + reds[1]) + (reds[2] + reds[3]);
  float inv = 1.0f / s;
  __syncthreads();  // all row reads complete before aliased writes
  bf16x8 o;
  #pragma unroll
  for (int k = 0; k < 8; ++k) o[k] = (__bf16)(e[k] * inv);
  *(bf16x8*)(dst + t * 8) = o;
}

// ---------------------------------------------------------------------------
extern "C" void kernel_launch(void* const* d_in, const int* in_sizes, int n_in,
                              void* d_out, int out_size, void* d_ws, size_t ws_size,
                              hipStream_t stream) {
  const float* q  = (const float*)d_in[0];  // [8,2048,1024]
  const float* y  = (const float*)d_in[1];  // [8,2048,1024]
  const float* Wq = (const float*)d_in[2];  // [1024,1024] (in,out)
  const float* Wk = (const float*)d_in[3];
  const float* Wv = (const float*)d_in[4];
  float* out = (float*)d_out;               // [8,2048,1024] f32

  char* ws = (char*)d_ws;
  const size_t MB = 1 << 20;
  // Persistent: vpT 0..32, qp 32..64, kp 64..96, weights 96..102.
  // Scratch @104MB: cast buffer first (32MB, q then y sequentially), then
  // scores chunks (16MB per batch, adaptive count from ws_size).
  __bf16* vpT = (__bf16*)(ws + 0 * MB);     // [8][1024][2048]
  __bf16* qp  = (__bf16*)(ws + 32 * MB);    // [8*2048][1024]
  __bf16* kp  = (__bf16*)(ws + 64 * MB);    // [8*2048][1024]
  __bf16* wqT = (__bf16*)(ws + 96 * MB);    // [out][in]
  __bf16* wkT = (__bf16*)(ws + 98 * MB);
  __bf16* wvT = (__bf16*)(ws + 100 * MB);
  char*   scratch = ws + 104 * MB;
  __bf16* castbuf = (__bf16*)scratch;       // 32 MB
  float*  sc      = (float*)scratch;        // scores chunk region

  const long NELEM = 8L * 2048 * 1024;  // 16M
  const size_t SC_PER_B = 2048L * 2048 * 4;  // 16 MB per batch of scores
  size_t avail = (ws_size > 104 * MB) ? ws_size - 104 * MB : 0;
  int nb = 1;                                // batches per scores chunk
  if (avail >= 8 * SC_PER_B) nb = 8;
  else if (avail >= 4 * SC_PER_B) nb = 4;
  else if (avail >= 2 * SC_PER_B) nb = 2;

  dim3 tg(32, 32);
  k_transpose_cast<<<tg, 256, 0, stream>>>(Wq, wqT, 1024, 1024);
  k_transpose_cast<<<tg, 256, 0, stream>>>(Wk, wkT, 1024, 1024);
  k_transpose_cast<<<tg, 256, 0, stream>>>(Wv, wvT, 1024, 1024);

  // cast q -> castbuf; G1: qp = q @ Wq   (M=16384, N=1024, K=1024)
  k_cast_bf16<<<8192, 256, 0, stream>>>(q, castbuf, NELEM);
  k_gemm_bt<1><<<dim3(8, 128, 1), 256, 0, stream>>>(castbuf, wqT, qp, 1024, 1024,
                                                    1024, 1024, 1.0f, 0, 0, 0);
  // cast y -> castbuf (reuse); G2: kp = y @ Wk
  k_cast_bf16<<<8192, 256, 0, stream>>>(y, castbuf, NELEM);
  k_gemm_bt<1><<<dim3(8, 128, 1), 256, 0, stream>>>(castbuf, wkT, kp, 1024, 1024,
                                                    1024, 1024, 1.0f, 0, 0, 0);
  // G3: vpT[b][f][m] = (kp @ Wv)^T   (batched, M=2048, N=1024)
  k_gemm_bt<2><<<dim3(8, 16, 8), 256, 0, stream>>>(kp, wvT, vpT, 1024, 1024, 2048,
                                                   1024, 1.0f, 2048L * 1024, 0,
                                                   1024L * 2048);

  // Chunked: G4 (scores) -> softmax -> G5 (attn @ vpT^T), nb batches at a time.
  for (int cb = 0; cb < 8; cb += nb) {
    // G4: sc[z][n][m] = qp[cb+z] @ kp[cb+z]^T / 32   (M=N=2048, K=1024), f32
    k_gemm_bt<0><<<dim3(16, 16, nb), 256, 0, stream>>>(
        qp + (long)cb * 2048 * 1024, kp + (long)cb * 2048 * 1024, sc, 1024, 1024,
        2048, 1024, 0.03125f, 2048L * 1024, 2048L * 1024, 2048L * 2048);
    // softmax rows, attn bf16 in-place (row pitch 4096 bf16)
    k_softmax_rows<<<nb * 2048, 256, 0, stream>>>(sc);
    // G5: out[cb+z][n][f] = attn[z] @ vpT[cb+z]^T (M=2048, N=1024, K=2048), f32
    k_gemm_bt<0><<<dim3(8, 16, nb), 256, 0, stream>>>(
        (const __bf16*)sc, vpT + (long)cb * 1024 * 2048,
        out + (long)cb * 2048 * 1024, 4096, 2048, 1024, 2048, 1.0f, 2048L * 4096,
        1024L * 2048, 2048L * 1024);
  }
}

// Round 3
// 484.719 us; speedup vs baseline: 1.2911x; 1.2911x over previous
//
#include <hip/hip_runtime.h>
#include <hip/hip_bf16.h>
#include <stdint.h>

typedef float f32x4 __attribute__((ext_vector_type(4)));
typedef __bf16 bf16x8 __attribute__((ext_vector_type(8)));
typedef __bf16 bf16x4 __attribute__((ext_vector_type(4)));

#define GLDS16(gp, lp) __builtin_amdgcn_global_load_lds( \
    (const __attribute__((address_space(1))) void*)(gp), \
    (__attribute__((address_space(3))) void*)(lp), 16, 0, 0)

// ---------------- cast fp32 -> bf16, vectorized x8 ----------------
__global__ __launch_bounds__(256) void k_cast_bf16(const float* __restrict__ in,
                                                   __bf16* __restrict__ out, long n) {
  long idx = ((long)blockIdx.x * blockDim.x + threadIdx.x) * 8;
  if (idx >= n) return;
  float4 a = *(const float4*)(in + idx);
  float4 b = *(const float4*)(in + idx + 4);
  bf16x8 o;
  o[0] = (__bf16)a.x; o[1] = (__bf16)a.y; o[2] = (__bf16)a.z; o[3] = (__bf16)a.w;
  o[4] = (__bf16)b.x; o[5] = (__bf16)b.y; o[6] = (__bf16)b.z; o[7] = (__bf16)b.w;
  *(bf16x8*)(out + idx) = o;
}

// ------------- transpose + cast: W[K][N] f32 -> WT[N][K] bf16 -------------
__global__ __launch_bounds__(256) void k_transpose_cast(const float* __restrict__ W,
                                                        __bf16* __restrict__ WT,
                                                        int K, int N) {
  __shared__ float tile[32][33];
  int n0 = blockIdx.x * 32, k0 = blockIdx.y * 32;
  int tx = threadIdx.x & 31, ty = threadIdx.x >> 5;
  #pragma unroll
  for (int r = 0; r < 32; r += 8)
    tile[ty + r][tx] = W[(long)(k0 + ty + r) * N + n0 + tx];
  __syncthreads();
  #pragma unroll
  for (int r = 0; r < 32; r += 8)
    WT[(long)(n0 + ty + r) * K + k0 + tx] = (__bf16)tile[tx][ty + r];
}

// ---------------- 8-phase-style GEMM: C[m][n] = scale * sum_k A[m][k]*B[n][k] ----
// BM=256, BN=128, BK=64. 512 threads = 8 waves (4M x 2N), per-wave 64x64 (acc 4x4).
// 3-slot LDS ring (3 x 48KB): compute K-tile t from slot t%3, stage t+2 into
// (t+2)%3 (held t-1, dead since t-1's closing barrier). vmcnt(6) once per K-tile.
// XOR swizzle: LDS chunk (16B) index ^= (row&7); inverse pre-applied to global src.
template <int OUT_MODE>  // 0 = f32 C[m][n], 1 = bf16 C[m][n], 2 = bf16 C^T[n][m]
__global__ __launch_bounds__(512, 2) void k_gemm8(
    const __bf16* __restrict__ A, const __bf16* __restrict__ B, void* __restrict__ Cv,
    int lda, int ldb, int ldc, int K, float scale, long sA, long sB, long sC,
    int gn, int per_b) {
  __shared__ __align__(16) char lds[3 * 49152];
  const int nwg = gridDim.x;
  const int bid = blockIdx.x;
  const int swz = (bid & 7) * (nwg >> 3) + (bid >> 3);  // bijective: nwg%8==0
  const int bz = swz / per_b;
  const int rem = swz - bz * per_b;
  const int m0 = (rem / gn) * 256, n0 = (rem % gn) * 128;
  A += (long)bz * sA;
  B += (long)bz * sB;

  const int tid = threadIdx.x;
  const int w = tid >> 6, l = tid & 63;
  const int wm = w >> 1, wn = w & 1;
  const int g = l >> 4, rp = l & 15;
  const int xr = (rp & 7) << 4;  // read-side byte xor

  // staging: lane covers row = rr*64 + w*8 + (l>>3), 16B chunk (l&7), src col
  // pre-swizzled so linear gload_lds dest + swizzled read agree.
  const int lr8 = l >> 3, lc = l & 7;
  const __bf16* asrc[4];
  #pragma unroll
  for (int rr = 0; rr < 4; ++rr) {
    int row = rr * 64 + w * 8 + lr8;
    asrc[rr] = A + (long)(m0 + row) * lda + ((lc ^ (row & 7)) << 3);
  }
  const __bf16* bsrc[2];
  #pragma unroll
  for (int rr = 0; rr < 2; ++rr) {
    int row = rr * 64 + w * 8 + lr8;
    bsrc[rr] = B + (long)(n0 + row) * ldb + ((lc ^ (row & 7)) << 3);
  }
  const int wdst = w * 1024;  // wave-uniform LDS dest offset

  f32x4 acc[4][4] = {};
  const int NT = K >> 6;

  // prologue: stage K-tiles 0 (slot 0) and 1 (slot 1); 12 loads/thread
  #pragma unroll
  for (int rr = 0; rr < 4; ++rr) GLDS16(asrc[rr], lds + (rr << 13) + wdst);
  #pragma unroll
  for (int rr = 0; rr < 2; ++rr) GLDS16(bsrc[rr], lds + 32768 + (rr << 13) + wdst);
  #pragma unroll
  for (int rr = 0; rr < 4; ++rr)
    GLDS16(asrc[rr] + 64, lds + 49152 + (rr << 13) + wdst);
  #pragma unroll
  for (int rr = 0; rr < 2; ++rr)
    GLDS16(bsrc[rr] + 64, lds + 49152 + 32768 + (rr << 13) + wdst);
  asm volatile("s_waitcnt vmcnt(6)" ::: "memory");  // slot0 resident (all lanes)
  asm volatile("s_barrier" ::: "memory");

  for (int t = 0; t < NT; ++t) {
    const char* As_ = lds + (t % 3) * 49152;
    const char* Bs_ = As_ + 32768;
    char* Sd = lds + ((t + 2) % 3) * 49152;
    const long soff = (t + 2 < NT) ? (long)(t + 2) * 64 : 0;  // tail: restage k0 (unread)

    bf16x8 af[4][2], bv[2][2];
    // ---- phase 0: A frags (kept for both phases) + B j=0,1; stage A(t+2) ----
    #pragma unroll
    for (int i = 0; i < 4; ++i)
      #pragma unroll
      for (int kk = 0; kk < 2; ++kk)
        af[i][kk] = *(const bf16x8*)(As_ + (wm * 64 + i * 16 + rp) * 128 +
                                     (((((kk << 2) | g) << 4)) ^ xr));
    #pragma unroll
    for (int jj = 0; jj < 2; ++jj)
      #pragma unroll
      for (int kk = 0; kk < 2; ++kk)
        bv[jj][kk] = *(const bf16x8*)(Bs_ + (wn * 64 + jj * 16 + rp) * 128 +
                                      (((((kk << 2) | g) << 4)) ^ xr));
    #pragma unroll
    for (int rr = 0; rr < 4; ++rr) GLDS16(asrc[rr] + soff, Sd + (rr << 13) + wdst);
    asm volatile("s_barrier" ::: "memory");
    asm volatile("s_waitcnt lgkmcnt(0)" ::: "memory");
    __builtin_amdgcn_s_setprio(1);
    #pragma unroll
    for (int i = 0; i < 4; ++i)
      #pragma unroll
      for (int jj = 0; jj < 2; ++jj)
        #pragma unroll
        for (int kk = 0; kk < 2; ++kk)
          acc[i][jj] = __builtin_amdgcn_mfma_f32_16x16x32_bf16(af[i][kk], bv[jj][kk],
                                                               acc[i][jj], 0, 0, 0);
    __builtin_amdgcn_s_setprio(0);
    asm volatile("s_barrier" ::: "memory");

    // ---- phase 1: B j=2,3; stage B(t+2); counted vmcnt(6) ----
    #pragma unroll
    for (int jj = 0; jj < 2; ++jj)
      #pragma unroll
      for (int kk = 0; kk < 2; ++kk)
        bv[jj][kk] = *(const bf16x8*)(Bs_ + (wn * 64 + (jj + 2) * 16 + rp) * 128 +
                                      (((((kk << 2) | g) << 4)) ^ xr));
    #pragma unroll
    for (int rr = 0; rr < 2; ++rr)
      GLDS16(bsrc[rr] + soff, Sd + 32768 + (rr << 13) + wdst);
    asm volatile("s_waitcnt vmcnt(6)" ::: "memory");  // K-tile t+1 fully resident
    asm volatile("s_barrier" ::: "memory");
    asm volatile("s_waitcnt lgkmcnt(0)" ::: "memory");
    __builtin_amdgcn_s_setprio(1);
    #pragma unroll
    for (int i = 0; i < 4; ++i)
      #pragma unroll
      for (int jj = 0; jj < 2; ++jj)
        #pragma unroll
        for (int kk = 0; kk < 2; ++kk)
          acc[i][jj + 2] = __builtin_amdgcn_mfma_f32_16x16x32_bf16(
              af[i][kk], bv[jj][kk], acc[i][jj + 2], 0, 0, 0);
    __builtin_amdgcn_s_setprio(0);
    asm volatile("s_barrier" ::: "memory");
  }
  asm volatile("s_waitcnt vmcnt(0)" ::: "memory");  // LDS lifetime: drain tail stages

  // C/D frag mapping (verified): col = lane&15, row = (lane>>4)*4 + reg
  const int crow = m0 + wm * 64 + g * 4;
  const int ccol = n0 + wn * 64 + rp;
  if constexpr (OUT_MODE == 0) {
    float* C = (float*)Cv + (long)bz * sC;
    #pragma unroll
    for (int i = 0; i < 4; ++i)
      #pragma unroll
      for (int j = 0; j < 4; ++j)
        #pragma unroll
        for (int rr = 0; rr < 4; ++rr)
          C[(long)(crow + i * 16 + rr) * ldc + ccol + j * 16] = acc[i][j][rr] * scale;
  } else if constexpr (OUT_MODE == 1) {
    __bf16* C = (__bf16*)Cv + (long)bz * sC;
    #pragma unroll
    for (int i = 0; i < 4; ++i)
      #pragma unroll
      for (int j = 0; j < 4; ++j)
        #pragma unroll
        for (int rr = 0; rr < 4; ++rr)
          C[(long)(crow + i * 16 + rr) * ldc + ccol + j * 16] =
              (__bf16)(acc[i][j][rr] * scale);
  } else {
    __bf16* C = (__bf16*)Cv + (long)bz * sC;
    #pragma unroll
    for (int i = 0; i < 4; ++i)
      #pragma unroll
      for (int j = 0; j < 4; ++j) {
        bf16x4 p;
        #pragma unroll
        for (int rr = 0; rr < 4; ++rr) p[rr] = (__bf16)(acc[i][j][rr] * scale);
        *(bf16x4*)&C[(long)(ccol + j * 16) * ldc + crow + i * 16] = p;
      }
  }
}

// ---------------- row softmax, fp32 in, bf16 out written in-place ----------------
__global__ __launch_bounds__(256) void k_softmax_rows(float* __restrict__ scores) {
  long row = blockIdx.x;
  float* src = scores + row * 2048;
  __bf16* dst = (__bf16*)src;
  int t = threadIdx.x, w = t >> 6, lane = t & 63;
  float4 v0 = *(const float4*)(src + t * 8);
  float4 v1 = *(const float4*)(src + t * 8 + 4);
  float vm = fmaxf(fmaxf(fmaxf(v0.x, v0.y), fmaxf(v0.z, v0.w)),
                   fmaxf(fmaxf(v1.x, v1.y), fmaxf(v1.z, v1.w)));
  #pragma unroll
  for (int off = 1; off < 64; off <<= 1) vm = fmaxf(vm, __shfl_xor(vm, off));
  __shared__ float redm[4], reds[4];
  if (lane == 0) redm[w] = vm;
  __syncthreads();
  vm = fmaxf(fmaxf(redm[0], redm[1]), fmaxf(redm[2], redm[3]));
  float e[8];
  e[0] = __expf(v0.x - vm); e[1] = __expf(v0.y - vm);
  e[2] = __expf(v0.z - vm); e[3] = __expf(v0.w - vm);
  e[4] = __expf(v1.x - vm); e[5] = __expf(v1.y - vm);
  e[6] = __expf(v1.z - vm); e[7] = __expf(v1.w - vm);
  float s = ((e[0] + e[1]) + (e[2] + e[3])) + ((e[4] + e[5]) + (e[6] + e[7]));
  #pragma unroll
  for (int off = 1; off < 64; off <<= 1) s += __shfl_xor(s, off);
  if (lane == 0) reds[w] = s;
  __syncthreads();
  s = (reds[0] + reds[1]) + (reds[2] + reds[3]);
  float inv = 1.0f / s;
  __syncthreads();  // all row reads complete before aliased writes
  bf16x8 o;
  #pragma unroll
  for (int k = 0; k < 8; ++k) o[k] = (__bf16)(e[k] * inv);
  *(bf16x8*)(dst + t * 8) = o;
}

// ---------------------------------------------------------------------------
extern "C" void kernel_launch(void* const* d_in, const int* in_sizes, int n_in,
                              void* d_out, int out_size, void* d_ws, size_t ws_size,
                              hipStream_t stream) {
  const float* q  = (const float*)d_in[0];
  const float* y  = (const float*)d_in[1];
  const float* Wq = (const float*)d_in[2];
  const float* Wk = (const float*)d_in[3];
  const float* Wv = (const float*)d_in[4];
  float* out = (float*)d_out;

  char* ws = (char*)d_ws;
  const size_t MB = 1 << 20;
  __bf16* vpT = (__bf16*)(ws + 0 * MB);     // [8][1024][2048]
  __bf16* qp  = (__bf16*)(ws + 32 * MB);    // [8*2048][1024]
  __bf16* kp  = (__bf16*)(ws + 64 * MB);    // [8*2048][1024]
  __bf16* wqT = (__bf16*)(ws + 96 * MB);
  __bf16* wkT = (__bf16*)(ws + 98 * MB);
  __bf16* wvT = (__bf16*)(ws + 100 * MB);
  char*   scratch = ws + 104 * MB;
  __bf16* castbuf = (__bf16*)scratch;       // 32 MB (q then y, sequential)
  float*  sc      = (float*)scratch;        // scores chunk region

  const long NELEM = 8L * 2048 * 1024;
  const size_t SC_PER_B = 2048L * 2048 * 4;  // 16 MB / batch
  size_t avail = (ws_size > 104 * MB) ? ws_size - 104 * MB : 0;
  int nb = 1;
  if (avail >= 8 * SC_PER_B) nb = 8;
  else if (avail >= 4 * SC_PER_B) nb = 4;
  else if (avail >= 2 * SC_PER_B) nb = 2;

  dim3 tg(32, 32);
  k_transpose_cast<<<tg, 256, 0, stream>>>(Wq, wqT, 1024, 1024);
  k_transpose_cast<<<tg, 256, 0, stream>>>(Wk, wkT, 1024, 1024);
  k_transpose_cast<<<tg, 256, 0, stream>>>(Wv, wvT, 1024, 1024);

  // G1: qp = q @ Wq   (M=16384, N=1024, K=1024): grid 64x8
  k_cast_bf16<<<8192, 256, 0, stream>>>(q, castbuf, NELEM);
  k_gemm8<1><<<512, 512, 0, stream>>>(castbuf, wqT, qp, 1024, 1024, 1024, 1024,
                                      1.0f, 0, 0, 0, 8, 512);
  // G2: kp = y @ Wk
  k_cast_bf16<<<8192, 256, 0, stream>>>(y, castbuf, NELEM);
  k_gemm8<1><<<512, 512, 0, stream>>>(castbuf, wkT, kp, 1024, 1024, 1024, 1024,
                                      1.0f, 0, 0, 0, 8, 512);
  // G3: vpT[b][f][m] = (kp @ Wv)^T   (batched, M=2048, N=1024): grid 8x8x8
  k_gemm8<2><<<512, 512, 0, stream>>>(kp, wvT, vpT, 1024, 1024, 2048, 1024, 1.0f,
                                      2048L * 1024, 0, 1024L * 2048, 8, 64);

  for (int cb = 0; cb < 8; cb += nb) {
    // G4: sc[z] = qp[cb+z] @ kp[cb+z]^T / 32  (M=N=2048, K=1024): grid 8x16 per b
    k_gemm8<0><<<128 * nb, 512, 0, stream>>>(
        qp + (long)cb * 2048 * 1024, kp + (long)cb * 2048 * 1024, sc, 1024, 1024,
        2048, 1024, 0.03125f, 2048L * 1024, 2048L * 1024, 2048L * 2048, 16, 128);
    k_softmax_rows<<<nb * 2048, 256, 0, stream>>>(sc);
    // G5: out[cb+z] = attn[z] @ vpT[cb+z]^T  (M=2048, N=1024, K=2048): grid 8x8
    k_gemm8<0><<<64 * nb, 512, 0, stream>>>(
        (const __bf16*)sc, vpT + (long)cb * 1024 * 2048,
        out + (long)cb * 2048 * 1024, 4096, 2048, 1024, 2048, 1.0f, 2048L * 4096,
        1024L * 2048, 2048L * 1024, 8, 64);
  }
}

// Round 4
// 460.526 us; speedup vs baseline: 1.3589x; 1.0525x over previous
//
#include <hip/hip_runtime.h>
#include <hip/hip_bf16.h>
#include <stdint.h>

typedef float f32x4 __attribute__((ext_vector_type(4)));
typedef __bf16 bf16x8 __attribute__((ext_vector_type(8)));
typedef __bf16 bf16x4 __attribute__((ext_vector_type(4)));

#define GLDS16(gp, lp) __builtin_amdgcn_global_load_lds( \
    (const __attribute__((address_space(1))) void*)(gp), \
    (__attribute__((address_space(3))) void*)(lp), 16, 0, 0)

// ---------------- cast fp32 -> bf16, vectorized x8 ----------------
__global__ __launch_bounds__(256) void k_cast_bf16(const float* __restrict__ in,
                                                   __bf16* __restrict__ out, long n) {
  long idx = ((long)blockIdx.x * blockDim.x + threadIdx.x) * 8;
  if (idx >= n) return;
  float4 a = *(const float4*)(in + idx);
  float4 b = *(const float4*)(in + idx + 4);
  bf16x8 o;
  o[0] = (__bf16)a.x; o[1] = (__bf16)a.y; o[2] = (__bf16)a.z; o[3] = (__bf16)a.w;
  o[4] = (__bf16)b.x; o[5] = (__bf16)b.y; o[6] = (__bf16)b.z; o[7] = (__bf16)b.w;
  *(bf16x8*)(out + idx) = o;
}

// ---- fused cast of two tensors (q,y) in one dispatch ----
__global__ __launch_bounds__(256) void k_cast2_bf16(const float* __restrict__ a,
                                                    const float* __restrict__ b,
                                                    __bf16* __restrict__ oa,
                                                    __bf16* __restrict__ ob, long n) {
  long idx = ((long)blockIdx.x * blockDim.x + threadIdx.x) * 8;
  const float* src;
  __bf16* dst;
  long i;
  if (idx < n) { src = a; dst = oa; i = idx; }
  else if (idx < 2 * n) { src = b; dst = ob; i = idx - n; }
  else return;
  float4 x = *(const float4*)(src + i);
  float4 z = *(const float4*)(src + i + 4);
  bf16x8 o;
  o[0] = (__bf16)x.x; o[1] = (__bf16)x.y; o[2] = (__bf16)x.z; o[3] = (__bf16)x.w;
  o[4] = (__bf16)z.x; o[5] = (__bf16)z.y; o[6] = (__bf16)z.z; o[7] = (__bf16)z.w;
  *(bf16x8*)(dst + i) = o;
}

// ------------- transpose + cast: W[K][N] f32 -> WT[N][K] bf16 -------------
__global__ __launch_bounds__(256) void k_transpose_cast(const float* __restrict__ W,
                                                        __bf16* __restrict__ WT,
                                                        int K, int N) {
  __shared__ float tile[32][33];
  int n0 = blockIdx.x * 32, k0 = blockIdx.y * 32;
  int tx = threadIdx.x & 31, ty = threadIdx.x >> 5;
  #pragma unroll
  for (int r = 0; r < 32; r += 8)
    tile[ty + r][tx] = W[(long)(k0 + ty + r) * N + n0 + tx];
  __syncthreads();
  #pragma unroll
  for (int r = 0; r < 32; r += 8)
    WT[(long)(n0 + ty + r) * K + k0 + tx] = (__bf16)tile[tx][ty + r];
}

// ---------------- phase-interleaved GEMM (proven round-3 core) ----------------
// C[m][n] = scale * sum_k A[m][k]*B[n][k].  BM=256, BN=128, BK=64.
// 512 threads = 8 waves (4M x 2N), per-wave 64x64 (acc 4x4 of 16x16x32 MFMA).
// 3-slot LDS ring (3 x 48KB): compute K-tile t from slot t%3, stage t+2 into
// (t+2)%3. vmcnt(6) once per K-tile (counted, never 0 in-loop).
// XOR swizzle on 16B chunks; inverse pre-applied to per-lane global source.
// TAG only disambiguates the symbol per call-site for per-GEMM profiling.
template <int OUT_MODE, int TAG>  // OUT_MODE: 0 f32 C, 1 bf16 C, 2 bf16 C^T
__global__ __launch_bounds__(512, 2) void k_gemm8(
    const __bf16* __restrict__ A, const __bf16* __restrict__ B, void* __restrict__ Cv,
    int lda, int ldb, int ldc, int K, float scale, long sA, long sB, long sC,
    int gn, int per_b) {
  __shared__ __align__(16) char lds[3 * 49152];
  const int nwg = gridDim.x;
  const int bid = blockIdx.x;
  const int swz = (bid & 7) * (nwg >> 3) + (bid >> 3);  // bijective: nwg%8==0
  const int bz = swz / per_b;
  const int rem = swz - bz * per_b;
  const int m0 = (rem / gn) * 256, n0 = (rem % gn) * 128;
  A += (long)bz * sA;
  B += (long)bz * sB;

  const int tid = threadIdx.x;
  const int w = tid >> 6, l = tid & 63;
  const int wm = w >> 1, wn = w & 1;
  const int g = l >> 4, rp = l & 15;
  const int xr = (rp & 7) << 4;  // read-side byte xor

  const int lr8 = l >> 3, lc = l & 7;
  const __bf16* asrc[4];
  #pragma unroll
  for (int rr = 0; rr < 4; ++rr) {
    int row = rr * 64 + w * 8 + lr8;
    asrc[rr] = A + (long)(m0 + row) * lda + ((lc ^ (row & 7)) << 3);
  }
  const __bf16* bsrc[2];
  #pragma unroll
  for (int rr = 0; rr < 2; ++rr) {
    int row = rr * 64 + w * 8 + lr8;
    bsrc[rr] = B + (long)(n0 + row) * ldb + ((lc ^ (row & 7)) << 3);
  }
  const int wdst = w * 1024;  // wave-uniform LDS dest offset

  f32x4 acc[4][4] = {};
  const int NT = K >> 6;

  // prologue: stage K-tiles 0 (slot 0) and 1 (slot 1)
  #pragma unroll
  for (int rr = 0; rr < 4; ++rr) GLDS16(asrc[rr], lds + (rr << 13) + wdst);
  #pragma unroll
  for (int rr = 0; rr < 2; ++rr) GLDS16(bsrc[rr], lds + 32768 + (rr << 13) + wdst);
  #pragma unroll
  for (int rr = 0; rr < 4; ++rr)
    GLDS16(asrc[rr] + 64, lds + 49152 + (rr << 13) + wdst);
  #pragma unroll
  for (int rr = 0; rr < 2; ++rr)
    GLDS16(bsrc[rr] + 64, lds + 49152 + 32768 + (rr << 13) + wdst);
  asm volatile("s_waitcnt vmcnt(6)" ::: "memory");  // slot0 resident
  asm volatile("s_barrier" ::: "memory");

  for (int t = 0; t < NT; ++t) {
    const char* As_ = lds + (t % 3) * 49152;
    const char* Bs_ = As_ + 32768;
    char* Sd = lds + ((t + 2) % 3) * 49152;
    const long soff = (t + 2 < NT) ? (long)(t + 2) * 64 : 0;  // tail: restage k0

    bf16x8 af[4][2], bv[2][2];
    // ---- phase 0: A frags (kept both phases) + B j=0,1; stage A(t+2) ----
    #pragma unroll
    for (int i = 0; i < 4; ++i)
      #pragma unroll
      for (int kk = 0; kk < 2; ++kk)
        af[i][kk] = *(const bf16x8*)(As_ + (wm * 64 + i * 16 + rp) * 128 +
                                     (((((kk << 2) | g) << 4)) ^ xr));
    #pragma unroll
    for (int jj = 0; jj < 2; ++jj)
      #pragma unroll
      for (int kk = 0; kk < 2; ++kk)
        bv[jj][kk] = *(const bf16x8*)(Bs_ + (wn * 64 + jj * 16 + rp) * 128 +
                                      (((((kk << 2) | g) << 4)) ^ xr));
    #pragma unroll
    for (int rr = 0; rr < 4; ++rr) GLDS16(asrc[rr] + soff, Sd + (rr << 13) + wdst);
    asm volatile("s_barrier" ::: "memory");
    asm volatile("s_waitcnt lgkmcnt(0)" ::: "memory");
    __builtin_amdgcn_s_setprio(1);
    #pragma unroll
    for (int i = 0; i < 4; ++i)
      #pragma unroll
      for (int jj = 0; jj < 2; ++jj)
        #pragma unroll
        for (int kk = 0; kk < 2; ++kk)
          acc[i][jj] = __builtin_amdgcn_mfma_f32_16x16x32_bf16(af[i][kk], bv[jj][kk],
                                                               acc[i][jj], 0, 0, 0);
    __builtin_amdgcn_s_setprio(0);
    asm volatile("s_barrier" ::: "memory");

    // ---- phase 1: B j=2,3; stage B(t+2); counted vmcnt(6) ----
    #pragma unroll
    for (int jj = 0; jj < 2; ++jj)
      #pragma unroll
      for (int kk = 0; kk < 2; ++kk)
        bv[jj][kk] = *(const bf16x8*)(Bs_ + (wn * 64 + (jj + 2) * 16 + rp) * 128 +
                                      (((((kk << 2) | g) << 4)) ^ xr));
    #pragma unroll
    for (int rr = 0; rr < 2; ++rr)
      GLDS16(bsrc[rr] + soff, Sd + 32768 + (rr << 13) + wdst);
    asm volatile("s_waitcnt vmcnt(6)" ::: "memory");  // K-tile t+1 fully resident
    asm volatile("s_barrier" ::: "memory");
    asm volatile("s_waitcnt lgkmcnt(0)" ::: "memory");
    __builtin_amdgcn_s_setprio(1);
    #pragma unroll
    for (int i = 0; i < 4; ++i)
      #pragma unroll
      for (int jj = 0; jj < 2; ++jj)
        #pragma unroll
        for (int kk = 0; kk < 2; ++kk)
          acc[i][jj + 2] = __builtin_amdgcn_mfma_f32_16x16x32_bf16(
              af[i][kk], bv[jj][kk], acc[i][jj + 2], 0, 0, 0);
    __builtin_amdgcn_s_setprio(0);
    asm volatile("s_barrier" ::: "memory");
  }
  asm volatile("s_waitcnt vmcnt(0)" ::: "memory");  // drain tail stages

  // C/D frag mapping: col = lane&15, row = (lane>>4)*4 + reg
  const int crow = m0 + wm * 64 + g * 4;
  const int ccol = n0 + wn * 64 + rp;
  if constexpr (OUT_MODE == 0) {
    float* C = (float*)Cv + (long)bz * sC;
    #pragma unroll
    for (int i = 0; i < 4; ++i)
      #pragma unroll
      for (int j = 0; j < 4; ++j)
        #pragma unroll
        for (int rr = 0; rr < 4; ++rr)
          C[(long)(crow + i * 16 + rr) * ldc + ccol + j * 16] = acc[i][j][rr] * scale;
  } else if constexpr (OUT_MODE == 1) {
    __bf16* C = (__bf16*)Cv + (long)bz * sC;
    #pragma unroll
    for (int i = 0; i < 4; ++i)
      #pragma unroll
      for (int j = 0; j < 4; ++j)
        #pragma unroll
        for (int rr = 0; rr < 4; ++rr)
          C[(long)(crow + i * 16 + rr) * ldc + ccol + j * 16] =
              (__bf16)(acc[i][j][rr] * scale);
  } else {
    __bf16* C = (__bf16*)Cv + (long)bz * sC;
    #pragma unroll
    for (int i = 0; i < 4; ++i)
      #pragma unroll
      for (int j = 0; j < 4; ++j) {
        bf16x4 p;
        #pragma unroll
        for (int rr = 0; rr < 4; ++rr) p[rr] = (__bf16)(acc[i][j][rr] * scale);
        *(bf16x4*)&C[(long)(ccol + j * 16) * ldc + crow + i * 16] = p;
      }
  }
}

// ---------------- row softmax, bf16 in, bf16 out, in-place ----------------
// one block per row of 2048 bf16 (4 KB). Each thread owns 8 elems; in-place
// write of its own elems only -> no cross-thread aliasing.
__global__ __launch_bounds__(256) void k_softmax_bf(__bf16* __restrict__ scores) {
  long row = blockIdx.x;
  __bf16* p = scores + row * 2048;
  int t = threadIdx.x, w = t >> 6, lane = t & 63;
  bf16x8 v = *(const bf16x8*)(p + t * 8);
  float e[8];
  #pragma unroll
  for (int k = 0; k < 8; ++k) e[k] = (float)v[k];
  float vm = fmaxf(fmaxf(fmaxf(e[0], e[1]), fmaxf(e[2], e[3])),
                   fmaxf(fmaxf(e[4], e[5]), fmaxf(e[6], e[7])));
  #pragma unroll
  for (int off = 1; off < 64; off <<= 1) vm = fmaxf(vm, __shfl_xor(vm, off));
  __shared__ float redm[4], reds[4];
  if (lane == 0) redm[w] = vm;
  __syncthreads();
  vm = fmaxf(fmaxf(redm[0], redm[1]), fmaxf(redm[2], redm[3]));
  float s = 0.f;
  #pragma unroll
  for (int k = 0; k < 8; ++k) { e[k] = __expf(e[k] - vm); s += e[k]; }
  #pragma unroll
  for (int off = 1; off < 64; off <<= 1) s += __shfl_xor(s, off);
  if (lane == 0) reds[w] = s;
  __syncthreads();
  s = (reds[0] + reds[1]) + (reds[2] + reds[3]);
  float inv = 1.0f / s;
  bf16x8 o;
  #pragma unroll
  for (int k = 0; k < 8; ++k) o[k] = (__bf16)(e[k] * inv);
  *(bf16x8*)(p + t * 8) = o;
}

// ---------------------------------------------------------------------------
extern "C" void kernel_launch(void* const* d_in, const int* in_sizes, int n_in,
                              void* d_out, int out_size, void* d_ws, size_t ws_size,
                              hipStream_t stream) {
  const float* q  = (const float*)d_in[0];
  const float* y  = (const float*)d_in[1];
  const float* Wq = (const float*)d_in[2];
  const float* Wk = (const float*)d_in[3];
  const float* Wv = (const float*)d_in[4];
  float* out = (float*)d_out;

  char* ws = (char*)d_ws;
  const size_t MB = 1 << 20;
  __bf16* vpT = (__bf16*)(ws + 0 * MB);     // [8][1024][2048]
  __bf16* qp  = (__bf16*)(ws + 32 * MB);    // [8*2048][1024]
  __bf16* kp  = (__bf16*)(ws + 64 * MB);    // [8*2048][1024]
  __bf16* wqT = (__bf16*)(ws + 96 * MB);
  __bf16* wkT = (__bf16*)(ws + 98 * MB);
  __bf16* wvT = (__bf16*)(ws + 100 * MB);

  const long NELEM = 8L * 2048 * 1024;          // 16M per tensor
  const size_t SC_PER_B = 2048L * 2048 * 2;     // 8 MB per batch (bf16 scores)
  const bool roomy = ws_size >= 232 * MB;       // parallel cast bufs + full scores

  __bf16* qbf;
  __bf16* ybf;
  __bf16* sc;
  int nb;
  if (roomy) {
    qbf = (__bf16*)(ws + 104 * MB);
    ybf = (__bf16*)(ws + 136 * MB);
    sc  = (__bf16*)(ws + 168 * MB);  // 64 MB
    nb = 8;
  } else {
    qbf = ybf = (__bf16*)(ws + 104 * MB);  // sequential reuse
    sc = (__bf16*)(ws + 104 * MB);         // reused after casts consumed
    size_t avail = (ws_size > 104 * MB) ? ws_size - 104 * MB : 0;
    nb = 1;
    if (avail >= 8 * SC_PER_B) nb = 8;
    else if (avail >= 4 * SC_PER_B) nb = 4;
    else if (avail >= 2 * SC_PER_B) nb = 2;
  }

  dim3 tg(32, 32);
  k_transpose_cast<<<tg, 256, 0, stream>>>(Wq, wqT, 1024, 1024);
  k_transpose_cast<<<tg, 256, 0, stream>>>(Wk, wkT, 1024, 1024);
  k_transpose_cast<<<tg, 256, 0, stream>>>(Wv, wvT, 1024, 1024);

  if (roomy) {
    k_cast2_bf16<<<16384, 256, 0, stream>>>(q, y, qbf, ybf, NELEM);
    // G1: qp = q @ Wq   (M=16384, N=1024, K=1024)
    k_gemm8<1, 1><<<512, 512, 0, stream>>>(qbf, wqT, qp, 1024, 1024, 1024, 1024,
                                           1.0f, 0, 0, 0, 8, 512);
    // G2: kp = y @ Wk
    k_gemm8<1, 2><<<512, 512, 0, stream>>>(ybf, wkT, kp, 1024, 1024, 1024, 1024,
                                           1.0f, 0, 0, 0, 8, 512);
  } else {
    k_cast_bf16<<<8192, 256, 0, stream>>>(q, qbf, NELEM);
    k_gemm8<1, 1><<<512, 512, 0, stream>>>(qbf, wqT, qp, 1024, 1024, 1024, 1024,
                                           1.0f, 0, 0, 0, 8, 512);
    k_cast_bf16<<<8192, 256, 0, stream>>>(y, ybf, NELEM);
    k_gemm8<1, 2><<<512, 512, 0, stream>>>(ybf, wkT, kp, 1024, 1024, 1024, 1024,
                                           1.0f, 0, 0, 0, 8, 512);
  }
  // G3: vpT[b][f][m] = (kp @ Wv)^T   (batched, M=2048, N=1024)
  k_gemm8<2, 3><<<512, 512, 0, stream>>>(kp, wvT, vpT, 1024, 1024, 2048, 1024, 1.0f,
                                         2048L * 1024, 0, 1024L * 2048, 8, 64);

  for (int cb = 0; cb < 8; cb += nb) {
    // G4: sc[z] = bf16( qp[cb+z] @ kp[cb+z]^T / 32 )  (M=N=2048, K=1024)
    k_gemm8<1, 4><<<128 * nb, 512, 0, stream>>>(
        qp + (long)cb * 2048 * 1024, kp + (long)cb * 2048 * 1024, sc, 1024, 1024,
        2048, 1024, 0.03125f, 2048L * 1024, 2048L * 1024, 2048L * 2048, 16, 128);
    // softmax rows in-place (bf16 -> bf16)
    k_softmax_bf<<<nb * 2048, 256, 0, stream>>>(sc);
    // G5: out[cb+z] = attn[z] @ vpT[cb+z]^T  (M=2048, N=1024, K=2048), f32 out
    k_gemm8<0, 5><<<64 * nb, 512, 0, stream>>>(
        sc, vpT + (long)cb * 1024 * 2048, out + (long)cb * 2048 * 1024, 2048, 2048,
        1024, 2048, 1.0f, 2048L * 2048, 1024L * 2048, 2048L * 1024, 8, 64);
  }
}